// Round 8
// baseline (186.057 us; speedup 1.0000x reference)
//
#include <hip/hip_runtime.h>
#include <stdint.h>

#define N_IMG 256
#define HW 196
#define CDIM 512

#define F_EPS_POS 0.65f
#define F_EPS_NEG 0.40f
#define F_INV_TAU (1.0f/0.03f)
#define F_TEMP 0.07f

typedef __attribute__((ext_vector_type(8))) short bf16x8;
typedef __attribute__((ext_vector_type(8))) unsigned short u16x8;
typedef __attribute__((ext_vector_type(4))) float f32x4;

__device__ __forceinline__ unsigned short f2bf(float x){
    unsigned int u = __float_as_uint(x);
    u = (u + 0x7FFFu + ((u >> 16) & 1u)) >> 16;
    return (unsigned short)u;
}
__device__ __forceinline__ float sigm(float x){ return 1.0f/(1.0f + __expf(-x)); }

// ---------------- kernel 1: audio L2-normalize -> bf16 ----------------
__global__ void audio_norm_k(const float* __restrict__ audio,
                             unsigned short* __restrict__ abf){
    int k = blockIdx.x, t = threadIdx.x;
    __shared__ float red[256];
    float v0 = audio[k*CDIM + t];
    float v1 = audio[k*CDIM + t + 256];
    red[t] = v0*v0 + v1*v1;
    __syncthreads();
    for (int s = 128; s > 0; s >>= 1){
        if (t < s) red[t] += red[t+s];
        __syncthreads();
    }
    float rrt = 1.0f / sqrtf(red[0]);
    abf[k*CDIM + t]       = f2bf(v0*rrt);
    abf[k*CDIM + t + 256] = f2bf(v1*rrt);
}

// ---------------- kernel 2: main GEMM + weighted reductions ----------------
// ROUND-8 MACRO-RESTRUCTURE. Rounds 0-7 (8 variants) were all "13 barrier-
// coupled 16-row tiles, K inner": every variant cost ~4.5us PER STEP
// regardless of in-step content -> the per-step overhead (stage chain +
// barrier + phase serialization) is the invariant, and it only amortizes
// with FEWER, FATTER steps (m233: 2-phase overhead ~72%, fixed per step).
// New shape: grid = 512 = (n, row-half). Each block: rows half*112..+111 of
// image n, K-loop of 8 steps x BK=64 channels. Per wave per step: 28 MFMAs
// (7 row-frags x 2 ks x 2 k-cols) -- accumulators persist across the K-loop.
// Only 8 barrier pairs (vs 13), staging per step = 64B/thread.
// B (audio) in regs: 32 x bf16x8 = 128 VGPR; acc 56; stage 16; ~225 total
// fits the 256-reg/2-wave budget (waves_per_eu(2,2)).
// Dot-product c-order identical to rounds 0-7 (B index j=2s+ks ascending).
// rnorm ss is accumulated during staging (different summation order: ~1e-7
// rel on rn; loss impact ~1e-6 -- first deliberate non-bitwise change).
// Row-halves write disjoint partial arrays (deterministic, no atomics);
// pd_k sums the two halves.
__global__ __launch_bounds__(512) __attribute__((amdgpu_waves_per_eu(2, 2)))
void main_k(const float* __restrict__ frame,
            const unsigned short* __restrict__ abf,
            float* __restrict__ np0, float* __restrict__ dp0,
            float* __restrict__ np1, float* __restrict__ dp1,
            float* __restrict__ hn_p0, float* __restrict__ hd_p0,
            float* __restrict__ hn_p1, float* __restrict__ hd_p1){
    __shared__ unsigned short A[2][112*72];   // 72-elem row stride: 144B -> 4-bank
    __shared__ float rnS[112];                 // rotation/row, 2-way max conflict

    const int t    = threadIdx.x;
    const int n    = blockIdx.x >> 1;
    const int half = blockIdx.x & 1;
    const int lane = t & 63, wid = t >> 6;     // wid 0..7
    const int col  = lane & 15, quad = lane >> 4;
    const int kg0  = wid*32 + col;             // this wave's two k columns
    const int kg1  = kg0 + 16;

    // ---- B fragments in registers (2 x 16 x bf16x8 = 128 VGPRs) ----
    bf16x8 B0[16], B1[16];
    {
        const unsigned short* b0p = abf + (size_t)kg0*CDIM + quad*8;
        const unsigned short* b1p = abf + (size_t)kg1*CDIM + quad*8;
        #pragma unroll
        for (int j = 0; j < 16; ++j){
            B0[j] = *(const bf16x8*)(b0p + j*32);
            B1[j] = *(const bf16x8*)(b1p + j*32);
        }
    }
#define ANCH8(a,b,c,d,e,f,g,h) \
    asm volatile("" : "+v"(a),"+v"(b),"+v"(c),"+v"(d),"+v"(e),"+v"(f),"+v"(g),"+v"(h))
    ANCH8(B0[0],B0[1],B0[2],B0[3],B0[4],B0[5],B0[6],B0[7]);
    ANCH8(B0[8],B0[9],B0[10],B0[11],B0[12],B0[13],B0[14],B0[15]);
    ANCH8(B1[0],B1[1],B1[2],B1[3],B1[4],B1[5],B1[6],B1[7]);
    ANCH8(B1[8],B1[9],B1[10],B1[11],B1[12],B1[13],B1[14],B1[15]);
#undef ANCH8

    // ---- staging identity: 4 threads per row, 16 channels each ----
    const int  srow = t >> 2;                  // 0..127, active < 112
    const int  sc   = (t & 3) * 16;            // channel offset within BK=64
    const bool sact = (srow < 112);
    int prow = half*112 + srow; if (prow > HW-1) prow = HW-1;  // clamp pad rows
    const float* gsrc = frame + ((size_t)n*HW + prow)*CDIM + sc;

    float ss = 0.f;                            // row sq-sum partial (128 c)
    float4 v[4];

    auto sload = [&](int s){
        if (sact){
            const float4* p = (const float4*)(gsrc + s*64);
            v[0] = p[0]; v[1] = p[1]; v[2] = p[2]; v[3] = p[3];
        }
    };
    auto sstore = [&](int buf){
        if (sact){
            ss += v[0].x*v[0].x + v[0].y*v[0].y + v[0].z*v[0].z + v[0].w*v[0].w
                + v[1].x*v[1].x + v[1].y*v[1].y + v[1].z*v[1].z + v[1].w*v[1].w
                + v[2].x*v[2].x + v[2].y*v[2].y + v[2].z*v[2].z + v[2].w*v[2].w
                + v[3].x*v[3].x + v[3].y*v[3].y + v[3].z*v[3].z + v[3].w*v[3].w;
            u16x8 w0 = { f2bf(v[0].x), f2bf(v[0].y), f2bf(v[0].z), f2bf(v[0].w),
                         f2bf(v[1].x), f2bf(v[1].y), f2bf(v[1].z), f2bf(v[1].w) };
            u16x8 w1 = { f2bf(v[2].x), f2bf(v[2].y), f2bf(v[2].z), f2bf(v[2].w),
                         f2bf(v[3].x), f2bf(v[3].y), f2bf(v[3].z), f2bf(v[3].w) };
            unsigned short* d = &A[buf][srow*72 + sc];
            *(u16x8*)(d)     = w0;
            *(u16x8*)(d + 8) = w1;
        }
    };

    f32x4 acc0[7], acc1[7];
    #pragma unroll
    for (int m = 0; m < 7; ++m){
        acc0[m] = (f32x4){0.f,0.f,0.f,0.f};
        acc1[m] = (f32x4){0.f,0.f,0.f,0.f};
    }

    sload(0); sstore(0);
    __syncthreads();

    // ---- K-loop: 8 steps of BK=64, accumulators persist ----
    #pragma unroll
    for (int s = 0; s < 8; ++s){
        if (s < 7) sload(s + 1);               // prefetch under MFMA phase
        const int buf = s & 1;
        #pragma unroll
        for (int m = 0; m < 7; ++m){
            #pragma unroll
            for (int ks = 0; ks < 2; ++ks){
                bf16x8 a = *(const bf16x8*)&A[buf][(m*16 + col)*72 + ks*32 + quad*8];
                acc0[m] = __builtin_amdgcn_mfma_f32_16x16x32_bf16(a, B0[2*s+ks], acc0[m], 0, 0, 0);
                acc1[m] = __builtin_amdgcn_mfma_f32_16x16x32_bf16(a, B1[2*s+ks], acc1[m], 0, 0, 0);
            }
        }
        if (s < 7) sstore((s + 1) & 1);        // implicit vmcnt before use
        __syncthreads();
    }

    // ---- row rsqrt: pair-reduce the 4 staging threads of each row ----
    ss += __shfl_xor(ss, 1, 64);
    ss += __shfl_xor(ss, 2, 64);
    if (sact && (t & 3) == 0)
        rnS[srow] = (ss > 0.f) ? (1.0f/sqrtf(ss)) : 0.f;
    __syncthreads();

    // ---- epilogue: weighted reductions over this block's valid rows ----
    float en0=0.f, en1=0.f, ed0=0.f, ed1=0.f;
    float hn0=0.f, hn1=0.f, hd0=0.f, hd1=0.f;
    #pragma unroll
    for (int m = 0; m < 7; ++m){
        #pragma unroll
        for (int rr = 0; rr < 4; ++rr){
            int row = m*16 + quad*4 + rr;      // 0..111
            int pr  = half*112 + row;
            if (pr < HW){
                float rn = rnS[row];
                float s0 = acc0[m][rr] * rn;
                float s1 = acc1[m][rr] * rn;
                float w0 = sigm((s0 - F_EPS_POS) * F_INV_TAU);
                float w1 = sigm((s1 - F_EPS_POS) * F_INV_TAU);
                en0 += w0*s0; ed0 += w0;
                en1 += w1*s1; ed1 += w1;
                if (kg0 == n){ float wn = 1.f - sigm((s0 - F_EPS_NEG) * F_INV_TAU); hn0 += wn*s0; hd0 += wn; }
                if (kg1 == n){ float wn = 1.f - sigm((s1 - F_EPS_NEG) * F_INV_TAU); hn1 += wn*s1; hd1 += wn; }
            }
        }
    }

    en0 += __shfl_xor(en0, 16, 64); en0 += __shfl_xor(en0, 32, 64);
    ed0 += __shfl_xor(ed0, 16, 64); ed0 += __shfl_xor(ed0, 32, 64);
    en1 += __shfl_xor(en1, 16, 64); en1 += __shfl_xor(en1, 32, 64);
    ed1 += __shfl_xor(ed1, 16, 64); ed1 += __shfl_xor(ed1, 32, 64);
    hn0 += __shfl_xor(hn0, 16, 64); hn0 += __shfl_xor(hn0, 32, 64);
    hd0 += __shfl_xor(hd0, 16, 64); hd0 += __shfl_xor(hd0, 32, 64);
    hn1 += __shfl_xor(hn1, 16, 64); hn1 += __shfl_xor(hn1, 32, 64);
    hd1 += __shfl_xor(hd1, 16, 64); hd1 += __shfl_xor(hd1, 32, 64);

    float* npH = half ? np1 : np0;
    float* dpH = half ? dp1 : dp0;
    if (quad == 0){
        npH[n*N_IMG + kg0] = en0;  dpH[n*N_IMG + kg0] = ed0;
        npH[n*N_IMG + kg1] = en1;  dpH[n*N_IMG + kg1] = ed1;
        if (kg0 == n){ (half?hn_p1:hn_p0)[n] = hn0; (half?hd_p1:hd_p0)[n] = hd0; }
        if (kg1 == n){ (half?hn_p1:hn_p0)[n] = hn1; (half?hd_p1:hd_p0)[n] = hd1; }
    }
}

// ---------------- kernel 3: per-n Pi_d / Ni_d (sums the two row-halves) ----------------
__global__ void pd_k(const float* __restrict__ np0, const float* __restrict__ dp0,
                     const float* __restrict__ np1, const float* __restrict__ dp1,
                     const float* __restrict__ hn_p0, const float* __restrict__ hd_p0,
                     const float* __restrict__ hn_p1, const float* __restrict__ hd_p1,
                     float* __restrict__ Pi_d, float* __restrict__ Ni_d){
    int nn = blockIdx.x, t = threadIdx.x;
    __shared__ float red[256];
    __shared__ float diagv;
    float ratio = (np0[nn*N_IMG + t] + np1[nn*N_IMG + t])
                / (dp0[nn*N_IMG + t] + dp1[nn*N_IMG + t]);
    if (t == nn) diagv = ratio;
    red[t] = ratio * (t == nn ? -99.f : 1.f);
    __syncthreads();
    for (int s = 128; s > 0; s >>= 1){
        if (t < s) red[t] += red[t+s];
        __syncthreads();
    }
    if (t == 0){
        Pi_d[nn] = F_TEMP * diagv;
        Ni_d[nn] = F_TEMP * ((hn_p0[nn]+hn_p1[nn])/(hd_p0[nn]+hd_p1[nn]) + red[0]);
    }
}

// ---------------- kernel 4: broadcast (N,N) log-sum + atomic total ----------------
__global__ void loss_k(const float* __restrict__ Pi_d, const float* __restrict__ Ni_d,
                       float* __restrict__ out){
    int i = blockIdx.x, j = threadIdx.x;
    __shared__ float red[256];
    float x = Ni_d[j] - Pi_d[i];
    red[j] = (x > 20.f) ? x : log1pf(__expf(x));
    __syncthreads();
    for (int s = 128; s > 0; s >>= 1){
        if (j < s) red[j] += red[j+s];
        __syncthreads();
    }
    if (j == 0) atomicAdd(out, red[0] * (1.0f/(float)N_IMG));
}

extern "C" void kernel_launch(void* const* d_in, const int* in_sizes, int n_in,
                              void* d_out, int out_size, void* d_ws, size_t ws_size,
                              hipStream_t stream) {
    const float* frame = (const float*)d_in[0];
    const float* audio = (const float*)d_in[1];
    float* out = (float*)d_out;
    char* ws = (char*)d_ws;

    unsigned short* abf  = (unsigned short*)(ws);           // 262144 B
    float* np0  = (float*)(ws + 262144);                    // 262144 B
    float* dp0  = (float*)(ws + 524288);                    // 262144 B
    float* np1  = (float*)(ws + 786432);                    // 262144 B
    float* dp1  = (float*)(ws + 1048576);                   // 262144 B
    float* hn0  = (float*)(ws + 1310720);                   // 1024 B
    float* hd0  = (float*)(ws + 1311744);                   // 1024 B
    float* hn1  = (float*)(ws + 1312768);                   // 1024 B
    float* hd1  = (float*)(ws + 1313792);                   // 1024 B
    float* Pi_d = (float*)(ws + 1314816);                   // 1024 B
    float* Ni_d = (float*)(ws + 1315840);                   // 1024 B

    hipMemsetAsync(out, 0, sizeof(float), stream);          // capture-legal

    audio_norm_k<<<N_IMG, 256, 0, stream>>>(audio, abf);
    main_k<<<N_IMG*2, 512, 0, stream>>>(frame, abf,
                                        np0, dp0, np1, dp1,
                                        hn0, hd0, hn1, hd1);
    pd_k<<<N_IMG, 256, 0, stream>>>(np0, dp0, np1, dp1,
                                    hn0, hd0, hn1, hd1, Pi_d, Ni_d);
    loss_k<<<N_IMG, 256, 0, stream>>>(Pi_d, Ni_d, out);
}